// Round 8
// baseline (124.795 us; speedup 1.0000x reference)
//
#include <hip/hip_runtime.h>

#define N_NODES 50000
#define E_EDGES 800000
#define F_IN    64
#define F_HID   256
#define F_OUT   64

#define BSZ       64      // nodes per bucket == MLP tile rows
#define NB        782     // ceil(50000/64) buckets
#define CAP       1536    // max edges per bucket handled (mean 1024, +16 sigma)
#define CHUNK     4096    // edges per bin chunk
#define EPB       16      // edges per thread in bin phase
#define NCHUNK    196     // ceil(E_EDGES/CHUNK)
#define X2B_ITEMS (N_NODES * F_IN / 8)   // 400000 short8s
#define X2B_B0    196
#define X2B_NB    570
#define X2B_PER   702     // ceil(400000/570); 570*702 = 400140
#define SWZ_B0    766     // 16 blocks x 4 tiles = 64 weight tiles
#define PREP_BLOCKS 782   // 196 bin + 570 x2b + 16 swizzle

#define SCALE_F   1048576.0f            // 2^20 fixed-point scale for LDS int accumulate
#define INV_SCALE 9.5367431640625e-07f  // 2^-20

typedef __attribute__((ext_vector_type(8))) short short8;  // 8 bf16 (4 VGPRs)
typedef __attribute__((ext_vector_type(4))) float f32x4;

__device__ inline unsigned short f2bf(float f) {
    unsigned int u = __float_as_uint(f);
    unsigned int r = u + 0x7FFF + ((u >> 16) & 1);   // round-to-nearest-even
    return (unsigned short)(r >> 16);
}
__device__ inline float bflo(unsigned int u) { return __uint_as_float(u << 16); }
__device__ inline float bfhi(unsigned int u) { return __uint_as_float(u & 0xFFFF0000u); }

// ---------- K1: bin+sort chunks | x->bf16 | W swizzle (no global atomics) ----------
// staging[chunk] holds the chunk's edges counting-sorted by bucket;
// meta[bucket][chunk] = cnt<<16 | start makes placement fully deterministic.
// Kernel boundary is the producer->consumer coherence point (R4/R7: cooperative
// single-kernel is dead — hipLaunchCooperativeKernel is dropped under graph capture).
__global__ __launch_bounds__(256) void prep_all(
        const int* __restrict__ src, const int* __restrict__ dst,
        unsigned int* __restrict__ staging,          // [NCHUNK][CHUNK] u32
        unsigned int* __restrict__ meta,             // [NB][NCHUNK] u32
        const float* __restrict__ x,
        unsigned short* __restrict__ xb,             // [N][64] bf16
        const float* __restrict__ W1, const float* __restrict__ W2,
        short8* __restrict__ Wp1, short8* __restrict__ Wp2) {
    int bx = blockIdx.x, tid = threadIdx.x;
    int lane = tid & 63, w = tid >> 6;

    if (bx >= SWZ_B0) {
        // ---- weight swizzle into MFMA B-fragment tiles ----
        int t = (bx - SWZ_B0) * 4 + w;
        int quad = lane >> 4, l16 = lane & 15;
        short8 v;
        if (t < 32) {
            int nb = t >> 1, kb = t & 1;
            #pragma unroll
            for (int j = 0; j < 8; ++j)
                v[j] = (short)f2bf(W1[(kb * 32 + quad * 8 + j) * F_HID + nb * 16 + l16]);
            Wp1[t * 64 + lane] = v;
        } else {
            int u = t - 32;
            int nb = u >> 3, kb = u & 7;
            #pragma unroll
            for (int j = 0; j < 8; ++j)
                v[j] = (short)f2bf(W2[(kb * 32 + quad * 8 + j) * F_OUT + nb * 16 + l16]);
            Wp2[u * 64 + lane] = v;
        }
        return;
    }
    if (bx >= X2B_B0) {
        // ---- x -> bf16 ----
        int base = (bx - X2B_B0) * X2B_PER;
        int lim = base + X2B_PER; if (lim > X2B_ITEMS) lim = X2B_ITEMS;
        for (int idx = base + tid; idx < lim; idx += 256) {
            float4 a = ((const float4*)x)[idx * 2 + 0];
            float4 b = ((const float4*)x)[idx * 2 + 1];
            short8 o;
            o[0] = (short)f2bf(a.x); o[1] = (short)f2bf(a.y);
            o[2] = (short)f2bf(a.z); o[3] = (short)f2bf(a.w);
            o[4] = (short)f2bf(b.x); o[5] = (short)f2bf(b.y);
            o[6] = (short)f2bf(b.z); o[7] = (short)f2bf(b.w);
            ((short8*)xb)[idx] = o;
        }
        return;
    }

    // ---- bin chunk bx: count, scan, counting-sort in LDS ----
    __shared__ int lcur[NB], lstart[NB];
    __shared__ unsigned int sortedp[CHUNK];          // 16 KB
    __shared__ int wtot[4];
    for (int i = tid; i < NB; i += 256) lcur[i] = 0;
    __syncthreads();
    int e0 = bx * CHUNK;
    int ec = E_EDGES - e0; if (ec > CHUNK) ec = CHUNK;
    unsigned int myp[EPB]; int myr[EPB];
    #pragma unroll
    for (int k = 0; k < EPB; ++k) {
        int i = k * 256 + tid;
        if (i < ec) {
            unsigned int d = (unsigned int)dst[e0 + i];
            unsigned int s = (unsigned int)src[e0 + i];
            myp[k] = (d << 16) | s;
            myr[k] = atomicAdd(&lcur[d >> 6], 1);    // int LDS atomics are native
        }
    }
    __syncthreads();
    int b4 = tid * 4;
    int a0 = (b4 + 0 < NB) ? lcur[b4 + 0] : 0;
    int a1 = (b4 + 1 < NB) ? lcur[b4 + 1] : 0;
    int a2 = (b4 + 2 < NB) ? lcur[b4 + 2] : 0;
    int a3 = (b4 + 3 < NB) ? lcur[b4 + 3] : 0;
    int seg = a0 + a1 + a2 + a3;
    int sc = seg;
    #pragma unroll
    for (int off = 1; off < 64; off <<= 1) {
        int u = __shfl_up(sc, off, 64);
        if (lane >= off) sc += u;
    }
    if (lane == 63) wtot[w] = sc;
    __syncthreads();
    int add = 0;
    #pragma unroll
    for (int k = 0; k < 4; ++k) if (k < w) add += wtot[k];
    int excl = add + sc - seg;
    if (b4 + 0 < NB) lstart[b4 + 0] = excl;
    if (b4 + 1 < NB) lstart[b4 + 1] = excl + a0;
    if (b4 + 2 < NB) lstart[b4 + 2] = excl + a0 + a1;
    if (b4 + 3 < NB) lstart[b4 + 3] = excl + a0 + a1 + a2;
    __syncthreads();
    #pragma unroll
    for (int k = 0; k < EPB; ++k) {
        int i = k * 256 + tid;
        if (i < ec) {
            int bb = myp[k] >> 22;                   // = dst >> 6
            sortedp[lstart[bb] + myr[k]] = myp[k];
        }
    }
    __syncthreads();
    // coalesced sequential chunk write + deterministic meta
    for (int i = tid; i < ec; i += 256) staging[(size_t)bx * CHUNK + i] = sortedp[i];
    for (int i = tid; i < NB; i += 256)
        meta[(size_t)i * NCHUNK + bx] = ((unsigned)lcur[i] << 16) | (unsigned)lstart[i];
}

// ---------- K2: per-bucket {meta scan, ingest, Q20 ds_add scatter-agg, MFMA MLP} ----------
// Aggregation is EDGE-PARALLEL via native int LDS atomicAdd (ds_add, no-return)
// into fixed-point Gint[64][65] (pad 65 => bank=(dst+feat)%32, spread by random dst).
// This deletes the rank/scan/reorder pipeline and its load imbalance entirely.
// (f32 LDS atomicAdd stays banned — it lowers to a CAS loop, R1 disaster.)
__global__ __launch_bounds__(256, 4) void bucket_mlp(
        const unsigned int* __restrict__ staging,
        const unsigned int* __restrict__ meta,
        const unsigned short* __restrict__ xb,
        const float* __restrict__ eps,
        const short8* __restrict__ Wp1,
        const float* __restrict__ b1,
        const short8* __restrict__ Wp2,
        const float* __restrict__ b2,
        float* __restrict__ out) {
    __shared__ int Gint[BSZ][65];                            // 16.6 KB Q20 accumulators
    __shared__ __align__(16) union {
        unsigned int ebuf[CAP];                              // 6 KB  bucket's packed edges
        unsigned short HsW[4][16][40];                       // 5.1 KB per-wave H chunk (MLP phase)
    } U;
    __shared__ int wtot[4];
    int b = blockIdx.x, tid = threadIdx.x;
    int lane = tid & 63, w = tid >> 6;

    // zero accumulators (4160 ints)
    for (int i = tid; i < BSZ * 65; i += 256) ((int*)Gint)[i] = 0;

    // per-chunk run table: coalesced meta read + 2-level exclusive scan (registers)
    int cnt_i = 0, st_i = 0;
    if (tid < NCHUNK) {
        unsigned int m = meta[(size_t)b * NCHUNK + tid];
        cnt_i = (int)(m >> 16); st_i = (int)(m & 0xFFFFu);
    }
    int sc2 = cnt_i;
    #pragma unroll
    for (int off = 1; off < 64; off <<= 1) {
        int u = __shfl_up(sc2, off, 64);
        if (lane >= off) sc2 += u;
    }
    if (lane == 63) wtot[w] = sc2;
    __syncthreads();
    int add2 = 0;
    #pragma unroll
    for (int k = 0; k < 4; ++k) if (k < w) add2 += wtot[k];
    int cofs = add2 + sc2 - cnt_i;                   // exclusive offset of this chunk's run
    int ecnt = wtot[0] + wtot[1] + wtot[2] + wtot[3];
    if (ecnt > CAP) ecnt = CAP;

    // ingest: copy this bucket's run from each chunk into ebuf (R5-verified pattern)
    {
        const unsigned int* srun = staging + (size_t)tid * CHUNK + st_i;
        for (int j = 0; j < cnt_i; ++j) {
            int pos = cofs + j;
            if (pos < CAP) U.ebuf[pos] = srun[j];
        }
    }
    __syncthreads();

    // ---- edge-parallel scatter-aggregate: 4 lanes/edge, 16 feats/lane, Q20 ds_add ----
    {
        int slot = tid >> 2, fi = tid & 3;
        const uint4* xv = (const uint4*)xb;
        unsigned int p0 = 0; uint4 u0 = {0,0,0,0}, u1 = {0,0,0,0};
        if (slot < ecnt) {
            p0 = U.ebuf[slot];
            int s = p0 & 0xFFFF;
            u0 = xv[s * 8 + fi * 2 + 0];
            u1 = xv[s * 8 + fi * 2 + 1];
        }
        for (int i = slot; i < ecnt; i += 64) {
            unsigned int pn = 0; uint4 un0 = {0,0,0,0}, un1 = {0,0,0,0};
            if (i + 64 < ecnt) {
                pn = U.ebuf[i + 64];
                int sn = pn & 0xFFFF;
                un0 = xv[sn * 8 + fi * 2 + 0];
                un1 = xv[sn * 8 + fi * 2 + 1];
            }
            int d = (p0 >> 16) & (BSZ - 1);
            int* g = &Gint[d][fi * 16];
            atomicAdd(&g[0],  __float2int_rn(bflo(u0.x) * SCALE_F));
            atomicAdd(&g[1],  __float2int_rn(bfhi(u0.x) * SCALE_F));
            atomicAdd(&g[2],  __float2int_rn(bflo(u0.y) * SCALE_F));
            atomicAdd(&g[3],  __float2int_rn(bfhi(u0.y) * SCALE_F));
            atomicAdd(&g[4],  __float2int_rn(bflo(u0.z) * SCALE_F));
            atomicAdd(&g[5],  __float2int_rn(bfhi(u0.z) * SCALE_F));
            atomicAdd(&g[6],  __float2int_rn(bflo(u0.w) * SCALE_F));
            atomicAdd(&g[7],  __float2int_rn(bfhi(u0.w) * SCALE_F));
            atomicAdd(&g[8],  __float2int_rn(bflo(u1.x) * SCALE_F));
            atomicAdd(&g[9],  __float2int_rn(bfhi(u1.x) * SCALE_F));
            atomicAdd(&g[10], __float2int_rn(bflo(u1.y) * SCALE_F));
            atomicAdd(&g[11], __float2int_rn(bfhi(u1.y) * SCALE_F));
            atomicAdd(&g[12], __float2int_rn(bflo(u1.z) * SCALE_F));
            atomicAdd(&g[13], __float2int_rn(bfhi(u1.z) * SCALE_F));
            atomicAdd(&g[14], __float2int_rn(bflo(u1.w) * SCALE_F));
            atomicAdd(&g[15], __float2int_rn(bfhi(u1.w) * SCALE_F));
            p0 = pn; u0 = un0; u1 = un1;
        }
    }
    __syncthreads();

    // ---- A-fragment build: Q20 -> float + (1+eps)*x fused, straight to registers ----
    int quad = lane >> 4, l16 = lane & 15;
    int lrow = w * 16 + l16;                         // local row 0..63
    int n = b * BSZ + lrow;
    int nc = n < N_NODES ? n : N_NODES - 1;          // clamp: garbage rows discarded at store
    const uint4* xv = (const uint4*)xb;
    float sc = 1.0f + eps[0];
    uint4 xq0 = xv[nc * 8 + quad];                   // feats quad*8 .. +7
    uint4 xq1 = xv[nc * 8 + 4 + quad];               // feats 32+quad*8 .. +7
    const int* gr0 = &Gint[lrow][quad * 8];
    const int* gr1 = &Gint[lrow][32 + quad * 8];
    short8 a0f, a1f;
    a0f[0] = (short)f2bf((float)gr0[0] * INV_SCALE + sc * bflo(xq0.x));
    a0f[1] = (short)f2bf((float)gr0[1] * INV_SCALE + sc * bfhi(xq0.x));
    a0f[2] = (short)f2bf((float)gr0[2] * INV_SCALE + sc * bflo(xq0.y));
    a0f[3] = (short)f2bf((float)gr0[3] * INV_SCALE + sc * bfhi(xq0.y));
    a0f[4] = (short)f2bf((float)gr0[4] * INV_SCALE + sc * bflo(xq0.z));
    a0f[5] = (short)f2bf((float)gr0[5] * INV_SCALE + sc * bfhi(xq0.z));
    a0f[6] = (short)f2bf((float)gr0[6] * INV_SCALE + sc * bflo(xq0.w));
    a0f[7] = (short)f2bf((float)gr0[7] * INV_SCALE + sc * bfhi(xq0.w));
    a1f[0] = (short)f2bf((float)gr1[0] * INV_SCALE + sc * bflo(xq1.x));
    a1f[1] = (short)f2bf((float)gr1[1] * INV_SCALE + sc * bfhi(xq1.x));
    a1f[2] = (short)f2bf((float)gr1[2] * INV_SCALE + sc * bflo(xq1.y));
    a1f[3] = (short)f2bf((float)gr1[3] * INV_SCALE + sc * bfhi(xq1.y));
    a1f[4] = (short)f2bf((float)gr1[4] * INV_SCALE + sc * bflo(xq1.z));
    a1f[5] = (short)f2bf((float)gr1[5] * INV_SCALE + sc * bfhi(xq1.z));
    a1f[6] = (short)f2bf((float)gr1[6] * INV_SCALE + sc * bflo(xq1.w));
    a1f[7] = (short)f2bf((float)gr1[7] * INV_SCALE + sc * bfhi(xq1.w));
    __syncthreads();   // ebuf reads done above; U.HsW writes begin below

    // ---- MLP: wave = 16-row stripe; H streamed in 32-col chunks ----
    // HsW[wave] is wave-private -> zero-cost wave_barrier instead of __syncthreads.
    f32x4 acc2[4];
    #pragma unroll
    for (int ob = 0; ob < 4; ++ob) acc2[ob] = (f32x4){0.f, 0.f, 0.f, 0.f};

    #pragma unroll
    for (int kb = 0; kb < 8; ++kb) {
        f32x4 h0 = {0.f, 0.f, 0.f, 0.f}, h1 = {0.f, 0.f, 0.f, 0.f};
        h0 = __builtin_amdgcn_mfma_f32_16x16x32_bf16(a0f, Wp1[((2 * kb + 0) * 2 + 0) * 64 + lane], h0, 0, 0, 0);
        h0 = __builtin_amdgcn_mfma_f32_16x16x32_bf16(a1f, Wp1[((2 * kb + 0) * 2 + 1) * 64 + lane], h0, 0, 0, 0);
        h1 = __builtin_amdgcn_mfma_f32_16x16x32_bf16(a0f, Wp1[((2 * kb + 1) * 2 + 0) * 64 + lane], h1, 0, 0, 0);
        h1 = __builtin_amdgcn_mfma_f32_16x16x32_bf16(a1f, Wp1[((2 * kb + 1) * 2 + 1) * 64 + lane], h1, 0, 0, 0);
        float bias0 = b1[(2 * kb + 0) * 16 + l16];
        float bias1 = b1[(2 * kb + 1) * 16 + l16];
        #pragma unroll
        for (int i = 0; i < 4; ++i) {
            U.HsW[w][quad * 4 + i][l16]      = f2bf(h0[i] + bias0);
            U.HsW[w][quad * 4 + i][16 + l16] = f2bf(h1[i] + bias1);
        }
        __builtin_amdgcn_sched_barrier(0);
        __builtin_amdgcn_wave_barrier();
        __builtin_amdgcn_sched_barrier(0);
        short8 af = *(const short8*)&U.HsW[w][l16][quad * 8];
        #pragma unroll
        for (int ob = 0; ob < 4; ++ob)
            acc2[ob] = __builtin_amdgcn_mfma_f32_16x16x32_bf16(af, Wp2[(ob * 8 + kb) * 64 + lane], acc2[ob], 0, 0, 0);
        __builtin_amdgcn_sched_barrier(0);
        __builtin_amdgcn_wave_barrier();
        __builtin_amdgcn_sched_barrier(0);
    }

    #pragma unroll
    for (int ob = 0; ob < 4; ++ob) {
        int col = ob * 16 + l16;
        float bias = b2[col];
        #pragma unroll
        for (int i = 0; i < 4; ++i) {
            int row = b * BSZ + w * 16 + quad * 4 + i;
            if (row < N_NODES) out[row * F_OUT + col] = acc2[ob][i] + bias;
        }
    }
}

extern "C" void kernel_launch(void* const* d_in, const int* in_sizes, int n_in,
                              void* d_out, int out_size, void* d_ws, size_t ws_size,
                              hipStream_t stream) {
    const float* x   = (const float*)d_in[0];
    const float* W1  = (const float*)d_in[1];
    const float* b1  = (const float*)d_in[2];
    const float* W2  = (const float*)d_in[3];
    const float* b2  = (const float*)d_in[4];
    const float* eps = (const float*)d_in[5];
    const int*   src = (const int*)d_in[6];
    const int*   dst = (const int*)d_in[7];
    float* out = (float*)d_out;

    // ws layout (bytes):
    //   0x0000000 xb       bf16 [50000][64]        (6.40 MB)
    //   0x0700000 Wp1 (32K) | 0x0710000 Wp2 (32K)
    //   0x0800000 staging  u32 [196][4096]         (3.21 MB)
    //   0x0B80000 meta     u32 [782][196]          (613 KB)
    char* base = (char*)d_ws;
    unsigned short* xb    = (unsigned short*)base;
    short8* Wp1           = (short8*)(base + 0x700000);
    short8* Wp2           = (short8*)(base + 0x710000);
    unsigned int* staging = (unsigned int*)(base + 0x800000);
    unsigned int* meta    = (unsigned int*)(base + 0xB80000);

    prep_all<<<PREP_BLOCKS, 256, 0, stream>>>(src, dst, staging, meta, x, xb, W1, W2, Wp1, Wp2);
    bucket_mlp<<<NB, 256, 0, stream>>>(staging, meta, xb, eps, Wp1, b1, Wp2, b2, out);
}

// Round 9
// 114.952 us; speedup vs baseline: 1.0856x; 1.0856x over previous
//
#include <hip/hip_runtime.h>

#define N_NODES 50000
#define E_EDGES 800000
#define F_IN    64
#define F_HID   256
#define F_OUT   64

#define BSZ       64      // nodes per bucket == MLP tile rows
#define NB        782     // ceil(50000/64) buckets
#define CAP       1536    // max edges per bucket handled (mean 1024, +16 sigma)
#define CHUNK     4096    // edges per bin chunk
#define EPB       16      // edges per thread in bin phase
#define NCHUNK    196     // ceil(E_EDGES/CHUNK)
#define X2B_ITEMS (N_NODES * F_IN / 8)   // 400000 short8s
#define X2B_B0    196
#define X2B_NB    570
#define X2B_PER   702     // ceil(400000/570); 570*702 = 400140
#define SWZ_B0    766     // 16 blocks x 4 tiles = 64 weight tiles
#define PREP_BLOCKS 782   // 196 bin + 570 x2b + 16 swizzle

typedef __attribute__((ext_vector_type(8))) short short8;  // 8 bf16 (4 VGPRs)
typedef __attribute__((ext_vector_type(4))) float f32x4;

__device__ inline unsigned short f2bf(float f) {
    unsigned int u = __float_as_uint(f);
    unsigned int r = u + 0x7FFF + ((u >> 16) & 1);   // round-to-nearest-even
    return (unsigned short)(r >> 16);
}
__device__ inline float bflo(unsigned int u) { return __uint_as_float(u << 16); }
__device__ inline float bfhi(unsigned int u) { return __uint_as_float(u & 0xFFFF0000u); }

// ---------- K1: bin+sort chunks | x->bf16 | W swizzle (no global atomics) ----------
// staging[chunk] holds the chunk's edges counting-sorted by bucket;
// meta[bucket][chunk] = cnt<<16 | start makes placement fully deterministic.
// Kernel boundary is the producer->consumer coherence point (R4/R7: cooperative
// single-kernel is dead — hipLaunchCooperativeKernel is dropped under graph capture).
__global__ __launch_bounds__(256) void prep_all(
        const int* __restrict__ src, const int* __restrict__ dst,
        unsigned int* __restrict__ staging,          // [NCHUNK][CHUNK] u32
        unsigned int* __restrict__ meta,             // [NB][NCHUNK] u32
        const float* __restrict__ x,
        unsigned short* __restrict__ xb,             // [N][64] bf16
        const float* __restrict__ W1, const float* __restrict__ W2,
        short8* __restrict__ Wp1, short8* __restrict__ Wp2) {
    int bx = blockIdx.x, tid = threadIdx.x;
    int lane = tid & 63, w = tid >> 6;

    if (bx >= SWZ_B0) {
        // ---- weight swizzle into MFMA B-fragment tiles ----
        int t = (bx - SWZ_B0) * 4 + w;
        int quad = lane >> 4, l16 = lane & 15;
        short8 v;
        if (t < 32) {
            int nb = t >> 1, kb = t & 1;
            #pragma unroll
            for (int j = 0; j < 8; ++j)
                v[j] = (short)f2bf(W1[(kb * 32 + quad * 8 + j) * F_HID + nb * 16 + l16]);
            Wp1[t * 64 + lane] = v;
        } else {
            int u = t - 32;
            int nb = u >> 3, kb = u & 7;
            #pragma unroll
            for (int j = 0; j < 8; ++j)
                v[j] = (short)f2bf(W2[(kb * 32 + quad * 8 + j) * F_OUT + nb * 16 + l16]);
            Wp2[u * 64 + lane] = v;
        }
        return;
    }
    if (bx >= X2B_B0) {
        // ---- x -> bf16 ----
        int base = (bx - X2B_B0) * X2B_PER;
        int lim = base + X2B_PER; if (lim > X2B_ITEMS) lim = X2B_ITEMS;
        for (int idx = base + tid; idx < lim; idx += 256) {
            float4 a = ((const float4*)x)[idx * 2 + 0];
            float4 b = ((const float4*)x)[idx * 2 + 1];
            short8 o;
            o[0] = (short)f2bf(a.x); o[1] = (short)f2bf(a.y);
            o[2] = (short)f2bf(a.z); o[3] = (short)f2bf(a.w);
            o[4] = (short)f2bf(b.x); o[5] = (short)f2bf(b.y);
            o[6] = (short)f2bf(b.z); o[7] = (short)f2bf(b.w);
            ((short8*)xb)[idx] = o;
        }
        return;
    }

    // ---- bin chunk bx: count, scan, counting-sort in LDS ----
    __shared__ int lcur[NB], lstart[NB];
    __shared__ unsigned int sortedp[CHUNK];          // 16 KB
    __shared__ int wtot[4];
    for (int i = tid; i < NB; i += 256) lcur[i] = 0;
    __syncthreads();
    int e0 = bx * CHUNK;
    int ec = E_EDGES - e0; if (ec > CHUNK) ec = CHUNK;
    unsigned int myp[EPB]; int myr[EPB];
    #pragma unroll
    for (int k = 0; k < EPB; ++k) {
        int i = k * 256 + tid;
        if (i < ec) {
            unsigned int d = (unsigned int)dst[e0 + i];
            unsigned int s = (unsigned int)src[e0 + i];
            myp[k] = (d << 16) | s;
            myr[k] = atomicAdd(&lcur[d >> 6], 1);    // int LDS atomics are native
        }
    }
    __syncthreads();
    int b4 = tid * 4;
    int a0 = (b4 + 0 < NB) ? lcur[b4 + 0] : 0;
    int a1 = (b4 + 1 < NB) ? lcur[b4 + 1] : 0;
    int a2 = (b4 + 2 < NB) ? lcur[b4 + 2] : 0;
    int a3 = (b4 + 3 < NB) ? lcur[b4 + 3] : 0;
    int seg = a0 + a1 + a2 + a3;
    int sc = seg;
    #pragma unroll
    for (int off = 1; off < 64; off <<= 1) {
        int u = __shfl_up(sc, off, 64);
        if (lane >= off) sc += u;
    }
    if (lane == 63) wtot[w] = sc;
    __syncthreads();
    int add = 0;
    #pragma unroll
    for (int k = 0; k < 4; ++k) if (k < w) add += wtot[k];
    int excl = add + sc - seg;
    if (b4 + 0 < NB) lstart[b4 + 0] = excl;
    if (b4 + 1 < NB) lstart[b4 + 1] = excl + a0;
    if (b4 + 2 < NB) lstart[b4 + 2] = excl + a0 + a1;
    if (b4 + 3 < NB) lstart[b4 + 3] = excl + a0 + a1 + a2;
    __syncthreads();
    #pragma unroll
    for (int k = 0; k < EPB; ++k) {
        int i = k * 256 + tid;
        if (i < ec) {
            int bb = myp[k] >> 22;                   // = dst >> 6
            sortedp[lstart[bb] + myr[k]] = myp[k];
        }
    }
    __syncthreads();
    // coalesced sequential chunk write + deterministic meta
    for (int i = tid; i < ec; i += 256) staging[(size_t)bx * CHUNK + i] = sortedp[i];
    for (int i = tid; i < NB; i += 256)
        meta[(size_t)i * NCHUNK + bx] = ((unsigned)lcur[i] << 16) | (unsigned)lstart[i];
}

// ---------- K2: per-bucket {meta scan, direct staging rank, reorder, gather, MFMA MLP} ----------
// Edge ingest: binary-search the run table (cofsS) so consecutive threads read
// consecutive staging addresses (coalesced), straight into registers.
// Register-accumulating gather beats per-feature LDS atomics (R8: 64 ds_add/edge
// regressed +7us) and f32 LDS atomicAdd is a CAS-loop disaster (R1).
__global__ __launch_bounds__(256, 4) void bucket_mlp(
        const unsigned int* __restrict__ staging,
        const unsigned int* __restrict__ meta,
        const unsigned short* __restrict__ xb,
        const float* __restrict__ eps,
        const short8* __restrict__ Wp1,
        const float* __restrict__ b1,
        const short8* __restrict__ Wp2,
        const float* __restrict__ b2,
        float* __restrict__ out) {
    __shared__ int cofsS[256];                               // exclusive run offsets (pad = total)
    __shared__ int stS[256];                                 // run start within chunk
    __shared__ int lcnt[BSZ], loff[BSZ];
    __shared__ unsigned short obuf[CAP];                     // 3 KB  src ids grouped by dst
    __shared__ __align__(16) unsigned short Gs[BSZ][72];     // 9.2 KB agg bf16
    __shared__ __align__(16) unsigned short HsW[4][16][40];  // 5.1 KB per-wave H chunk
    __shared__ int wtot[4];
    int b = blockIdx.x, tid = threadIdx.x;
    int lane = tid & 63, w = tid >> 6;

    // per-chunk run table: coalesced meta read + 2-level exclusive scan
    int cnt_i = 0, st_i = 0;
    if (tid < NCHUNK) {
        unsigned int m = meta[(size_t)b * NCHUNK + tid];
        cnt_i = (int)(m >> 16); st_i = (int)(m & 0xFFFFu);
    }
    if (tid < BSZ) lcnt[tid] = 0;
    int sc2 = cnt_i;
    #pragma unroll
    for (int off = 1; off < 64; off <<= 1) {
        int u = __shfl_up(sc2, off, 64);
        if (lane >= off) sc2 += u;
    }
    if (lane == 63) wtot[w] = sc2;
    __syncthreads();
    int add2 = 0;
    #pragma unroll
    for (int k = 0; k < 4; ++k) if (k < w) add2 += wtot[k];
    cofsS[tid] = add2 + sc2 - cnt_i;     // exclusive; == total for tid >= NCHUNK (cnt 0)
    stS[tid] = st_i;
    int ecnt = wtot[0] + wtot[1] + wtot[2] + wtot[3];
    if (ecnt > CAP) ecnt = CAP;
    __syncthreads();

    // rank: load edges straight from staging (coalesced via run binary-search)
    unsigned int mp[6]; int mr[6];
    #pragma unroll
    for (int k = 0; k < 6; ++k) {
        int i = tid + k * 256;
        if (i < ecnt) {
            int lo = 0;                  // largest c with cofsS[c] <= i (cofsS[0]=0)
            #pragma unroll
            for (int s = 128; s > 0; s >>= 1) {
                int mid = lo + s;
                if (mid < 256 && cofsS[mid] <= i) lo = mid;
            }
            unsigned int p = staging[(size_t)lo * CHUNK + stS[lo] + (i - cofsS[lo])];
            mp[k] = p;
            mr[k] = atomicAdd(&lcnt[(p >> 16) & (BSZ - 1)], 1);
        }
    }
    __syncthreads();
    if (tid < BSZ) {
        int v = lcnt[tid];
        int s = v;
        #pragma unroll
        for (int off = 1; off < 64; off <<= 1) {
            int u = __shfl_up(s, off, 64);
            if (tid >= off) s += u;
        }
        loff[tid] = s - v;
    }
    __syncthreads();
    #pragma unroll
    for (int k = 0; k < 6; ++k) {
        int i = tid + k * 256;
        if (i < ecnt) {
            int d = (mp[k] >> 16) & (BSZ - 1);
            obuf[loff[d] + mr[k]] = (unsigned short)(mp[k] & 0xFFFFu);
        }
    }
    __syncthreads();

    // ---- gather: 4 lanes per node (lane owns 16 feats = 2 uint4) ----
    {
        int nl = tid >> 2;
        int fi = tid & 3;
        int n = b * BSZ + nl;
        float acc[16] = {};
        if (n < N_NODES) {
            const uint4* xv = (const uint4*)xb;
            int start = loff[nl];
            int cnt   = lcnt[nl];
            int j = 0;
            for (; j + 2 <= cnt; j += 2) {
                int s0 = obuf[start + j + 0];
                int s1 = obuf[start + j + 1];
                uint4 u0 = xv[s0 * 8 + fi * 2 + 0];
                uint4 u1 = xv[s0 * 8 + fi * 2 + 1];
                uint4 u2 = xv[s1 * 8 + fi * 2 + 0];
                uint4 u3 = xv[s1 * 8 + fi * 2 + 1];
                acc[0] += bflo(u0.x); acc[1] += bfhi(u0.x);
                acc[2] += bflo(u0.y); acc[3] += bfhi(u0.y);
                acc[4] += bflo(u0.z); acc[5] += bfhi(u0.z);
                acc[6] += bflo(u0.w); acc[7] += bfhi(u0.w);
                acc[8]  += bflo(u1.x); acc[9]  += bfhi(u1.x);
                acc[10] += bflo(u1.y); acc[11] += bfhi(u1.y);
                acc[12] += bflo(u1.z); acc[13] += bfhi(u1.z);
                acc[14] += bflo(u1.w); acc[15] += bfhi(u1.w);
                acc[0] += bflo(u2.x); acc[1] += bfhi(u2.x);
                acc[2] += bflo(u2.y); acc[3] += bfhi(u2.y);
                acc[4] += bflo(u2.z); acc[5] += bfhi(u2.z);
                acc[6] += bflo(u2.w); acc[7] += bfhi(u2.w);
                acc[8]  += bflo(u3.x); acc[9]  += bfhi(u3.x);
                acc[10] += bflo(u3.y); acc[11] += bfhi(u3.y);
                acc[12] += bflo(u3.z); acc[13] += bfhi(u3.z);
                acc[14] += bflo(u3.w); acc[15] += bfhi(u3.w);
            }
            if (j < cnt) {
                int s0 = obuf[start + j];
                uint4 u0 = xv[s0 * 8 + fi * 2 + 0];
                uint4 u1 = xv[s0 * 8 + fi * 2 + 1];
                acc[0] += bflo(u0.x); acc[1] += bfhi(u0.x);
                acc[2] += bflo(u0.y); acc[3] += bfhi(u0.y);
                acc[4] += bflo(u0.z); acc[5] += bfhi(u0.z);
                acc[6] += bflo(u0.w); acc[7] += bfhi(u0.w);
                acc[8]  += bflo(u1.x); acc[9]  += bfhi(u1.x);
                acc[10] += bflo(u1.y); acc[11] += bfhi(u1.y);
                acc[12] += bflo(u1.z); acc[13] += bfhi(u1.z);
                acc[14] += bflo(u1.w); acc[15] += bfhi(u1.w);
            }
            float sc = 1.0f + eps[0];
            uint4 m0 = xv[n * 8 + fi * 2 + 0];
            uint4 m1 = xv[n * 8 + fi * 2 + 1];
            acc[0] += sc * bflo(m0.x); acc[1] += sc * bfhi(m0.x);
            acc[2] += sc * bflo(m0.y); acc[3] += sc * bfhi(m0.y);
            acc[4] += sc * bflo(m0.z); acc[5] += sc * bfhi(m0.z);
            acc[6] += sc * bflo(m0.w); acc[7] += sc * bfhi(m0.w);
            acc[8]  += sc * bflo(m1.x); acc[9]  += sc * bfhi(m1.x);
            acc[10] += sc * bflo(m1.y); acc[11] += sc * bfhi(m1.y);
            acc[12] += sc * bflo(m1.z); acc[13] += sc * bfhi(m1.z);
            acc[14] += sc * bflo(m1.w); acc[15] += sc * bfhi(m1.w);
        }
        short8 o0, o1;
        #pragma unroll
        for (int k = 0; k < 8; ++k) { o0[k] = (short)f2bf(acc[k]); o1[k] = (short)f2bf(acc[8 + k]); }
        *(short8*)&Gs[nl][fi * 16 + 0] = o0;
        *(short8*)&Gs[nl][fi * 16 + 8] = o1;
    }
    __syncthreads();

    // ---- MLP: wave = 16-row stripe; H streamed in 32-col chunks ----
    // HsW[wave] is wave-private -> zero-cost wave_barrier instead of __syncthreads.
    int quad = lane >> 4, l16 = lane & 15;
    short8 a0f = *(const short8*)&Gs[w * 16 + l16][quad * 8];
    short8 a1f = *(const short8*)&Gs[w * 16 + l16][32 + quad * 8];

    f32x4 acc2[4];
    #pragma unroll
    for (int ob = 0; ob < 4; ++ob) acc2[ob] = (f32x4){0.f, 0.f, 0.f, 0.f};

    #pragma unroll
    for (int kb = 0; kb < 8; ++kb) {
        f32x4 h0 = {0.f, 0.f, 0.f, 0.f}, h1 = {0.f, 0.f, 0.f, 0.f};
        h0 = __builtin_amdgcn_mfma_f32_16x16x32_bf16(a0f, Wp1[((2 * kb + 0) * 2 + 0) * 64 + lane], h0, 0, 0, 0);
        h0 = __builtin_amdgcn_mfma_f32_16x16x32_bf16(a1f, Wp1[((2 * kb + 0) * 2 + 1) * 64 + lane], h0, 0, 0, 0);
        h1 = __builtin_amdgcn_mfma_f32_16x16x32_bf16(a0f, Wp1[((2 * kb + 1) * 2 + 0) * 64 + lane], h1, 0, 0, 0);
        h1 = __builtin_amdgcn_mfma_f32_16x16x32_bf16(a1f, Wp1[((2 * kb + 1) * 2 + 1) * 64 + lane], h1, 0, 0, 0);
        float bias0 = b1[(2 * kb + 0) * 16 + l16];
        float bias1 = b1[(2 * kb + 1) * 16 + l16];
        #pragma unroll
        for (int i = 0; i < 4; ++i) {
            HsW[w][quad * 4 + i][l16]      = f2bf(h0[i] + bias0);
            HsW[w][quad * 4 + i][16 + l16] = f2bf(h1[i] + bias1);
        }
        __builtin_amdgcn_sched_barrier(0);
        __builtin_amdgcn_wave_barrier();
        __builtin_amdgcn_sched_barrier(0);
        short8 af = *(const short8*)&HsW[w][l16][quad * 8];
        #pragma unroll
        for (int ob = 0; ob < 4; ++ob)
            acc2[ob] = __builtin_amdgcn_mfma_f32_16x16x32_bf16(af, Wp2[(ob * 8 + kb) * 64 + lane], acc2[ob], 0, 0, 0);
        __builtin_amdgcn_sched_barrier(0);
        __builtin_amdgcn_wave_barrier();
        __builtin_amdgcn_sched_barrier(0);
    }

    #pragma unroll
    for (int ob = 0; ob < 4; ++ob) {
        int col = ob * 16 + l16;
        float bias = b2[col];
        #pragma unroll
        for (int i = 0; i < 4; ++i) {
            int row = b * BSZ + w * 16 + quad * 4 + i;
            if (row < N_NODES) out[row * F_OUT + col] = acc2[ob][i] + bias;
        }
    }
}

extern "C" void kernel_launch(void* const* d_in, const int* in_sizes, int n_in,
                              void* d_out, int out_size, void* d_ws, size_t ws_size,
                              hipStream_t stream) {
    const float* x   = (const float*)d_in[0];
    const float* W1  = (const float*)d_in[1];
    const float* b1  = (const float*)d_in[2];
    const float* W2  = (const float*)d_in[3];
    const float* b2  = (const float*)d_in[4];
    const float* eps = (const float*)d_in[5];
    const int*   src = (const int*)d_in[6];
    const int*   dst = (const int*)d_in[7];
    float* out = (float*)d_out;

    // ws layout (bytes):
    //   0x0000000 xb       bf16 [50000][64]        (6.40 MB)
    //   0x0700000 Wp1 (32K) | 0x0710000 Wp2 (32K)
    //   0x0800000 staging  u32 [196][4096]         (3.21 MB)
    //   0x0B80000 meta     u32 [782][196]          (613 KB)
    char* base = (char*)d_ws;
    unsigned short* xb    = (unsigned short*)base;
    short8* Wp1           = (short8*)(base + 0x700000);
    short8* Wp2           = (short8*)(base + 0x710000);
    unsigned int* staging = (unsigned int*)(base + 0x800000);
    unsigned int* meta    = (unsigned int*)(base + 0xB80000);

    prep_all<<<PREP_BLOCKS, 256, 0, stream>>>(src, dst, staging, meta, x, xb, W1, W2, Wp1, Wp2);
    bucket_mlp<<<NB, 256, 0, stream>>>(staging, meta, xb, eps, Wp1, b1, Wp2, b2, out);
}